// Round 3
// baseline (305.191 us; speedup 1.0000x reference)
//
#include <hip/hip_runtime.h>
#include <math.h>

// Problem constants (fixed by the reference)
#define INC   256
#define OUTC  256
#define NHEAD 4
#define CPH   64

typedef __attribute__((ext_vector_type(4))) float  f32x4;
typedef __attribute__((ext_vector_type(8))) short  short8;
typedef __attribute__((ext_vector_type(4))) unsigned short usx4;
typedef __attribute__((ext_vector_type(8))) unsigned short usx8;

__device__ __forceinline__ float bf2f(unsigned short u) {
    union { unsigned int i; float f; } c; c.i = ((unsigned int)u) << 16; return c.f;
}
__device__ __forceinline__ unsigned short f2bf(float f) {
    union { float f; unsigned int i; } c; c.f = f;
    unsigned int x = c.i;
    unsigned int r = (x + 0x7FFFu + ((x >> 16) & 1u)) >> 16;  // round-nearest-even
    return (unsigned short)r;
}

// ---- build WbT [512][256] bf16 (transposed, cols 0-255 = W_gat, 256-511 = w_ft) ----
__global__ __launch_bounds__(256) void k_convert_w(const float* __restrict__ Wg,
                                                   const float* __restrict__ Wf,
                                                   unsigned short* __restrict__ wbt) {
    int idx = blockIdx.x * blockDim.x + threadIdx.x;
    if (idx >= 512 * 256) return;
    int c = idx >> 8;        // output column 0..511
    int k = idx & 255;       // k 0..255
    float v = (c < 256) ? Wg[k * 256 + c] : Wf[k * 256 + (c - 256)];
    wbt[idx] = f2bf(v);      // wbt[c*256 + k]
}

// ---------------- fused GEMM: [h | transformed] = x @ [W_gat | w_ft] ----------------
// Reads x as f32, converts to bf16 in-register during LDS staging (no xb buffer).
#define BM 128
#define BN 128
#define BK 32
__global__ __launch_bounds__(256) void k_gemm(
    const float* __restrict__ x,              // [M][256] f32
    const unsigned short* __restrict__ wbt,   // [512][256] bf16 (col-major weights)
    unsigned short* __restrict__ hb,          // [M][256] bf16 (GAT h)
    float* __restrict__ out,                  // [M][256] f32 (transformed -> d_out)
    const float* __restrict__ b_ft, const float* __restrict__ bn_g,
    const float* __restrict__ bn_b, const float* __restrict__ bn_m,
    const float* __restrict__ bn_v, int M) {
    __shared__ unsigned short As[BM][BK + 8];   // 40-short rows (80 B)
    __shared__ unsigned short Bs[BN][BK + 8];
    const int t = threadIdx.x;
    const int w = t >> 6, lane = t & 63;
    const int wr = w >> 1, wc = w & 1;          // 2x2 wave grid, 64x64 per wave
    const int bm0 = blockIdx.x * BM;
    const int bn0 = blockIdx.y * BN;            // 0,128 -> h; 256,384 -> transformed
    const int kg = lane >> 4;                   // 0..3
    const int lm = lane & 15;

    f32x4 acc[4][4] = {};

    for (int k0 = 0; k0 < 256; k0 += BK) {
        f32x4 a0[2], a1[2];
        usx8 bv[2];
#pragma unroll
        for (int s = 0; s < 2; s++) {
            int seg = t + s * 256;              // 0..511
            int row = seg >> 2;                 // 0..127
            int off = (seg & 3) * 8;            // 0,8,16,24
            int grow = bm0 + row; if (grow >= M) grow = M - 1;
            const float* ap = x + (long)grow * 256 + k0 + off;
            a0[s] = *(const f32x4*)ap;
            a1[s] = *(const f32x4*)(ap + 4);
            bv[s] = *(const usx8*)(wbt + (long)(bn0 + row) * 256 + k0 + off);
        }
        __syncthreads();
#pragma unroll
        for (int s = 0; s < 2; s++) {
            int seg = t + s * 256;
            int row = seg >> 2;
            int off = (seg & 3) * 8;
            usx8 av;
            av[0] = f2bf(a0[s][0]); av[1] = f2bf(a0[s][1]);
            av[2] = f2bf(a0[s][2]); av[3] = f2bf(a0[s][3]);
            av[4] = f2bf(a1[s][0]); av[5] = f2bf(a1[s][1]);
            av[6] = f2bf(a1[s][2]); av[7] = f2bf(a1[s][3]);
            *(usx8*)&As[row][off] = av;
            *(usx8*)&Bs[row][off] = bv[s];
        }
        __syncthreads();
        short8 afr[4], bfr[4];
#pragma unroll
        for (int mi = 0; mi < 4; mi++)
            afr[mi] = *(const short8*)&As[wr * 64 + mi * 16 + lm][kg * 8];
#pragma unroll
        for (int nj = 0; nj < 4; nj++)
            bfr[nj] = *(const short8*)&Bs[wc * 64 + nj * 16 + lm][kg * 8];
#pragma unroll
        for (int mi = 0; mi < 4; mi++)
#pragma unroll
            for (int nj = 0; nj < 4; nj++)
                acc[mi][nj] = __builtin_amdgcn_mfma_f32_16x16x32_bf16(
                    afr[mi], bfr[nj], acc[mi][nj], 0, 0, 0);
        __syncthreads();
    }

    const bool isH = (bn0 < 256);
#pragma unroll
    for (int mi = 0; mi < 4; mi++) {
#pragma unroll
        for (int nj = 0; nj < 4; nj++) {
            int col = bn0 + wc * 64 + nj * 16 + lm;
            f32x4 a = acc[mi][nj];
            int rowbase = bm0 + wr * 64 + mi * 16 + kg * 4;
            if (isH) {
#pragma unroll
                for (int r = 0; r < 4; r++) {
                    int row = rowbase + r;
                    if (row < M) hb[(long)row * 256 + col] = f2bf(a[r]);
                }
            } else {
                int c2 = col - 256;
                float bft = b_ft[c2], mu = bn_m[c2];
                float iv = rsqrtf(bn_v[c2] + 1e-5f);
                float g = bn_g[c2], bt = bn_b[c2];
#pragma unroll
                for (int r = 0; r < 4; r++) {
                    int row = rowbase + r;
                    if (row < M) {
                        float v = (a[r] + bft - mu) * iv * g + bt;
                        out[(long)row * 256 + c2] = v > 0.f ? v : 0.f;
                    }
                }
            }
        }
    }
}

// ---------------- per-node attention coefficients: a_src/a_dst [N][4] ----------------
__global__ __launch_bounds__(256) void k_attn(const unsigned short* __restrict__ hb,
                                              const float* __restrict__ att_s,
                                              const float* __restrict__ att_d,
                                              float* __restrict__ a_src,
                                              float* __restrict__ a_dst, int N) {
    int gid = blockIdx.x * 256 + threadIdx.x;
    int node = gid >> 6;
    int lane = threadIdx.x & 63;
    if (node >= N) return;
    usx4 hv = ((const usx4*)(hb + (long)node * 256))[lane];
    int head = lane >> 4;
    int cb = (lane & 15) * 4;
    float s1 = 0.f, s2 = 0.f;
#pragma unroll
    for (int j = 0; j < 4; j++) {
        float h = bf2f(hv[j]);
        s1 += h * att_s[head * 64 + cb + j];
        s2 += h * att_d[head * 64 + cb + j];
    }
#pragma unroll
    for (int o = 1; o < 16; o <<= 1) {
        s1 += __shfl_xor(s1, o);
        s2 += __shfl_xor(s2, o);
    }
    if ((lane & 15) == 0) {
        a_src[node * 4 + head] = s1;
        a_dst[node * 4 + head] = s2;
    }
}

// ---------------- CSR build (edge_index is int32 per harness convention) ----------------
__global__ void k_zero2(int* a, int* b, int n) {
    int i = blockIdx.x * blockDim.x + threadIdx.x;
    if (i < n) { a[i] = 0; b[i] = 0; }
}
__global__ void k_count(const int* __restrict__ ei, int* __restrict__ deg,
                        int E, int N) {
    int i = blockIdx.x * blockDim.x + threadIdx.x;
    if (i >= E + N) return;
    int d = (i < E) ? ei[E + i] : (i - E);
    atomicAdd(&deg[d], 1);
}
__global__ __launch_bounds__(256) void k_scan1(const int* __restrict__ deg,
                                               int* __restrict__ offs,
                                               int* __restrict__ bsum, int n) {
    __shared__ int tmp[256];
    int b = blockIdx.x, t = threadIdx.x;
    int base = b * 1024;
    int v[4];
#pragma unroll
    for (int j = 0; j < 4; j++) {
        int i = base + t * 4 + j;
        v[j] = (i < n) ? deg[i] : 0;
    }
    int local = v[0] + v[1] + v[2] + v[3];
    tmp[t] = local;
    __syncthreads();
    for (int off = 1; off < 256; off <<= 1) {
        int xv = (t >= off) ? tmp[t - off] : 0;
        __syncthreads();
        tmp[t] += xv;
        __syncthreads();
    }
    int run = tmp[t] - local;
    if (t == 255) bsum[b] = tmp[255];
#pragma unroll
    for (int j = 0; j < 4; j++) {
        int i = base + t * 4 + j;
        if (i < n) offs[i] = run;
        run += v[j];
    }
}
__global__ void k_scan2(int* bsum, int nb) {
    if (threadIdx.x == 0 && blockIdx.x == 0) {
        int acc = 0;
        for (int i = 0; i < nb; i++) { int x = bsum[i]; bsum[i] = acc; acc += x; }
    }
}
__global__ void k_scan3(int* offs, const int* bsum, int n) {
    int i = blockIdx.x * blockDim.x + threadIdx.x;
    if (i < n) offs[i] += bsum[i >> 10];
}
__global__ void k_scatter(const int* __restrict__ ei, const int* __restrict__ offs,
                          int* __restrict__ cursor, int* __restrict__ eids, int E, int N) {
    int i = blockIdx.x * blockDim.x + threadIdx.x;
    if (i >= E + N) return;
    int d = (i < E) ? ei[E + i] : (i - E);
    int pos = atomicAdd(&cursor[d], 1);
    eids[offs[d] + pos] = i;
}

// ---------------- softmax + aggregation: one block per destination node ----------------
#define CH 128
__global__ __launch_bounds__(256) void k_agg(
    const int* __restrict__ offs, const int* __restrict__ eids,
    const int* __restrict__ ei, const unsigned short* __restrict__ hb,
    const float4* __restrict__ a_src4, const float4* __restrict__ a_dst4,
    const float* __restrict__ bias_gat, float* __restrict__ out, int N, int E) {
    const int n = blockIdx.x;
    const int t = threadIdx.x;
    const int head = t >> 6;
    const int lane = t & 63;
    const int ETOT = E + N;
    int beg = offs[n];
    int end = (n + 1 < N) ? offs[n + 1] : ETOT;

    __shared__ int   s_src[CH];
    __shared__ float s_w[CH][4];
    __shared__ float s_m[4];

    float4 adv = a_dst4[n];
    float ad[4] = {adv.x, adv.y, adv.z, adv.w};
    float m_run = -INFINITY, den = 0.f, acc = 0.f;

    for (int base = beg; base < end; base += CH) {
        int len = min(CH, end - base);
        if (t < len) {
            int e = eids[base + t];
            int src = (e < E) ? ei[e] : (e - E);
            s_src[t] = src;
            float4 asv = a_src4[src];
            float av[4] = {asv.x, asv.y, asv.z, asv.w};
#pragma unroll
            for (int h = 0; h < 4; h++) {
                float l = av[h] + ad[h];
                l = l > 0.f ? l : 0.2f * l;     // LeakyReLU(0.2)
                s_w[t][h] = l;
            }
        }
        __syncthreads();
        // wave `head` reduces head `head`
        float cm = -INFINITY;
        for (int i = lane; i < len; i += 64) cm = fmaxf(cm, s_w[i][head]);
#pragma unroll
        for (int o = 32; o >= 1; o >>= 1) cm = fmaxf(cm, __shfl_xor(cm, o));
        float m_new = fmaxf(m_run, cm);
        float scale = __expf(m_run - m_new);   // 0 on first chunk (m_run=-inf)
        if (lane == 0) s_m[head] = m_new;
        __syncthreads();
        if (t < len) {
#pragma unroll
            for (int h = 0; h < 4; h++) s_w[t][h] = __expf(s_w[t][h] - s_m[h]);
        }
        __syncthreads();
        float cs = 0.f;
        for (int i = lane; i < len; i += 64) cs += s_w[i][head];
#pragma unroll
        for (int o = 32; o >= 1; o >>= 1) cs += __shfl_xor(cs, o);
        den = den * scale + cs;
        acc *= scale;
        for (int i = 0; i < len; i++) {
            float wgt = s_w[i][head];
            acc += wgt * bf2f(hb[(long)s_src[i] * 256 + t]);
        }
        m_run = m_new;
        __syncthreads();
    }
    long oidx = (long)n * 256 + t;
    out[oidx] = acc / (den + 1e-16f) + bias_gat[t] + out[oidx];
}

extern "C" void kernel_launch(void* const* d_in, const int* in_sizes, int n_in,
                              void* d_out, int out_size, void* d_ws, size_t ws_size,
                              hipStream_t stream) {
    const float* x        = (const float*)d_in[0];
    const int*   ei       = (const int*)d_in[1];     // harness delivers integers as int32
    const float* W_gat    = (const float*)d_in[4];
    const float* att_src  = (const float*)d_in[5];
    const float* att_dst  = (const float*)d_in[6];
    const float* bias_gat = (const float*)d_in[7];
    const float* w_ft     = (const float*)d_in[12];
    const float* b_ft     = (const float*)d_in[13];
    const float* bn_g     = (const float*)d_in[14];
    const float* bn_b     = (const float*)d_in[15];
    const float* bn_m     = (const float*)d_in[16];
    const float* bn_v     = (const float*)d_in[17];
    float* out = (float*)d_out;

    const int N = in_sizes[0] / 256;
    const int E = in_sizes[1] / 2;
    const int ETOT = E + N;

    // workspace carving (256B aligned) — total ~31.6 MB
    char* p = (char*)d_ws;
    auto alloc = [&](size_t bytes) {
        void* r = (void*)p;
        p += (bytes + 255) & ~(size_t)255;
        return r;
    };
    unsigned short* wbt  = (unsigned short*)alloc((size_t)512 * 256 * 2);
    unsigned short* hb   = (unsigned short*)alloc((size_t)N * 256 * 2);
    float* a_src = (float*)alloc((size_t)N * 4 * 4);
    float* a_dst = (float*)alloc((size_t)N * 4 * 4);
    int* deg    = (int*)alloc((size_t)N * 4);
    int* cursor = (int*)alloc((size_t)N * 4);
    int* offs   = (int*)alloc((size_t)(N + 1) * 4);
    int* bsum   = (int*)alloc((size_t)256 * 4);
    int* eids   = (int*)alloc((size_t)ETOT * 4);

    k_convert_w<<<(512 * 256 + 255) / 256, 256, 0, stream>>>(W_gat, w_ft, wbt);

    dim3 gg((N + BM - 1) / BM, 4);
    k_gemm<<<gg, 256, 0, stream>>>(x, wbt, hb, out, b_ft, bn_g, bn_b, bn_m, bn_v, N);

    k_attn<<<(N + 3) / 4, 256, 0, stream>>>(hb, att_src, att_dst, a_src, a_dst, N);

    k_zero2<<<(N + 255) / 256, 256, 0, stream>>>(deg, cursor, N);
    k_count<<<(ETOT + 255) / 256, 256, 0, stream>>>(ei, deg, E, N);
    int nb = (N + 1023) / 1024;
    k_scan1<<<nb, 256, 0, stream>>>(deg, offs, bsum, N);
    k_scan2<<<1, 64, 0, stream>>>(bsum, nb);
    k_scan3<<<(N + 255) / 256, 256, 0, stream>>>(offs, bsum, N);
    k_scatter<<<(ETOT + 255) / 256, 256, 0, stream>>>(ei, offs, cursor, eids, E, N);

    k_agg<<<N, 256, 0, stream>>>(offs, eids, ei, hb, (const float4*)a_src,
                                 (const float4*)a_dst, bias_gat, out, N, E);
}

// Round 4
// 274.797 us; speedup vs baseline: 1.1106x; 1.1106x over previous
//
#include <hip/hip_runtime.h>
#include <math.h>

typedef __attribute__((ext_vector_type(4))) float  f32x4;
typedef __attribute__((ext_vector_type(8))) short  short8;
typedef __attribute__((ext_vector_type(4))) unsigned short usx4;
typedef __attribute__((ext_vector_type(8))) unsigned short usx8;

__device__ __forceinline__ float bf2f(unsigned short u) {
    union { unsigned int i; float f; } c; c.i = ((unsigned int)u) << 16; return c.f;
}
__device__ __forceinline__ unsigned short f2bf(float f) {
    union { float f; unsigned int i; } c; c.f = f;
    unsigned int x = c.i;
    unsigned int r = (x + 0x7FFFu + ((x >> 16) & 1u)) >> 16;  // round-nearest-even
    return (unsigned short)r;
}

// ---- build WbT [512][256] bf16 (transposed, cols 0-255 = W_gat, 256-511 = w_ft) ----
__global__ __launch_bounds__(256) void k_convert_w(const float* __restrict__ Wg,
                                                   const float* __restrict__ Wf,
                                                   unsigned short* __restrict__ wbt) {
    int idx = blockIdx.x * blockDim.x + threadIdx.x;
    if (idx >= 512 * 256) return;
    int c = idx >> 8;
    int k = idx & 255;
    float v = (c < 256) ? Wg[k * 256 + c] : Wf[k * 256 + (c - 256)];
    wbt[idx] = f2bf(v);
}

// ---------------- fused GEMM: [h | transformed] = x @ [W_gat | w_ft] ----------------
#define BM 128
#define BN 128
#define BK 32
__global__ __launch_bounds__(256) void k_gemm(
    const float* __restrict__ x,              // [M][256] f32
    const unsigned short* __restrict__ wbt,   // [512][256] bf16
    unsigned short* __restrict__ hb,          // [M][256] bf16 (GAT h)
    unsigned short* __restrict__ tb,          // [M][256] bf16 transformed (or null)
    float* __restrict__ out,                  // fallback f32 transformed target
    const float* __restrict__ b_ft, const float* __restrict__ bn_g,
    const float* __restrict__ bn_b, const float* __restrict__ bn_m,
    const float* __restrict__ bn_v, int M) {
    __shared__ unsigned short As[BM][BK + 8];
    __shared__ unsigned short Bs[BN][BK + 8];
    const int t = threadIdx.x;
    const int w = t >> 6, lane = t & 63;
    const int wr = w >> 1, wc = w & 1;
    const int bm0 = blockIdx.x * BM;
    const int bn0 = blockIdx.y * BN;
    const int kg = lane >> 4;
    const int lm = lane & 15;

    f32x4 acc[4][4] = {};

    for (int k0 = 0; k0 < 256; k0 += BK) {
        f32x4 a0[2], a1[2];
        usx8 bv[2];
#pragma unroll
        for (int s = 0; s < 2; s++) {
            int seg = t + s * 256;
            int row = seg >> 2;
            int off = (seg & 3) * 8;
            int grow = bm0 + row; if (grow >= M) grow = M - 1;
            const float* ap = x + (long)grow * 256 + k0 + off;
            a0[s] = *(const f32x4*)ap;
            a1[s] = *(const f32x4*)(ap + 4);
            bv[s] = *(const usx8*)(wbt + (long)(bn0 + row) * 256 + k0 + off);
        }
        __syncthreads();
#pragma unroll
        for (int s = 0; s < 2; s++) {
            int seg = t + s * 256;
            int row = seg >> 2;
            int off = (seg & 3) * 8;
            usx8 av;
            av[0] = f2bf(a0[s][0]); av[1] = f2bf(a0[s][1]);
            av[2] = f2bf(a0[s][2]); av[3] = f2bf(a0[s][3]);
            av[4] = f2bf(a1[s][0]); av[5] = f2bf(a1[s][1]);
            av[6] = f2bf(a1[s][2]); av[7] = f2bf(a1[s][3]);
            *(usx8*)&As[row][off] = av;
            *(usx8*)&Bs[row][off] = bv[s];
        }
        __syncthreads();
        short8 afr[4], bfr[4];
#pragma unroll
        for (int mi = 0; mi < 4; mi++)
            afr[mi] = *(const short8*)&As[wr * 64 + mi * 16 + lm][kg * 8];
#pragma unroll
        for (int nj = 0; nj < 4; nj++)
            bfr[nj] = *(const short8*)&Bs[wc * 64 + nj * 16 + lm][kg * 8];
#pragma unroll
        for (int mi = 0; mi < 4; mi++)
#pragma unroll
            for (int nj = 0; nj < 4; nj++)
                acc[mi][nj] = __builtin_amdgcn_mfma_f32_16x16x32_bf16(
                    afr[mi], bfr[nj], acc[mi][nj], 0, 0, 0);
        __syncthreads();
    }

    const bool isH = (bn0 < 256);
#pragma unroll
    for (int mi = 0; mi < 4; mi++) {
#pragma unroll
        for (int nj = 0; nj < 4; nj++) {
            int col = bn0 + wc * 64 + nj * 16 + lm;
            f32x4 a = acc[mi][nj];
            int rowbase = bm0 + wr * 64 + mi * 16 + kg * 4;
            if (isH) {
#pragma unroll
                for (int r = 0; r < 4; r++) {
                    int row = rowbase + r;
                    if (row < M) hb[(long)row * 256 + col] = f2bf(a[r]);
                }
            } else {
                int c2 = col - 256;
                float bft = b_ft[c2], mu = bn_m[c2];
                float iv = rsqrtf(bn_v[c2] + 1e-5f);
                float g = bn_g[c2], bt = bn_b[c2];
#pragma unroll
                for (int r = 0; r < 4; r++) {
                    int row = rowbase + r;
                    if (row < M) {
                        float v = (a[r] + bft - mu) * iv * g + bt;
                        v = v > 0.f ? v : 0.f;
                        if (tb) tb[(long)row * 256 + c2] = f2bf(v);
                        else    out[(long)row * 256 + c2] = v;
                    }
                }
            }
        }
    }
}

// ---------------- per-node attention coefficients: a_src/a_dst [N][4] ----------------
__global__ __launch_bounds__(256) void k_attn(const unsigned short* __restrict__ hb,
                                              const float* __restrict__ att_s,
                                              const float* __restrict__ att_d,
                                              float* __restrict__ a_src,
                                              float* __restrict__ a_dst, int N) {
    int gid = blockIdx.x * 256 + threadIdx.x;
    int node = gid >> 6;
    int lane = threadIdx.x & 63;
    if (node >= N) return;
    usx4 hv = ((const usx4*)(hb + (long)node * 256))[lane];
    int head = lane >> 4;
    int cb = (lane & 15) * 4;
    float s1 = 0.f, s2 = 0.f;
#pragma unroll
    for (int j = 0; j < 4; j++) {
        float h = bf2f(hv[j]);
        s1 += h * att_s[head * 64 + cb + j];
        s2 += h * att_d[head * 64 + cb + j];
    }
#pragma unroll
    for (int o = 1; o < 16; o <<= 1) {
        s1 += __shfl_xor(s1, o);
        s2 += __shfl_xor(s2, o);
    }
    if ((lane & 15) == 0) {
        a_src[node * 4 + head] = s1;
        a_dst[node * 4 + head] = s2;
    }
}

// ---------------- CSR build (edge_index is int32) ----------------
__global__ void k_zero2(int* a, int* b, int n) {
    int i = blockIdx.x * blockDim.x + threadIdx.x;
    if (i < n) { a[i] = 0; b[i] = 0; }
}
__global__ void k_count(const int* __restrict__ ei, int* __restrict__ deg,
                        int E, int N) {
    int i = blockIdx.x * blockDim.x + threadIdx.x;
    if (i >= E + N) return;
    int d = (i < E) ? ei[E + i] : (i - E);
    atomicAdd(&deg[d], 1);
}
__global__ __launch_bounds__(256) void k_scan1(const int* __restrict__ deg,
                                               int* __restrict__ offs,
                                               int* __restrict__ bsum, int n) {
    __shared__ int tmp[256];
    int b = blockIdx.x, t = threadIdx.x;
    int base = b * 1024;
    int v[4];
#pragma unroll
    for (int j = 0; j < 4; j++) {
        int i = base + t * 4 + j;
        v[j] = (i < n) ? deg[i] : 0;
    }
    int local = v[0] + v[1] + v[2] + v[3];
    tmp[t] = local;
    __syncthreads();
    for (int off = 1; off < 256; off <<= 1) {
        int xv = (t >= off) ? tmp[t - off] : 0;
        __syncthreads();
        tmp[t] += xv;
        __syncthreads();
    }
    int run = tmp[t] - local;
    if (t == 255) bsum[b] = tmp[255];
#pragma unroll
    for (int j = 0; j < 4; j++) {
        int i = base + t * 4 + j;
        if (i < n) offs[i] = run;
        run += v[j];
    }
}
__global__ void k_scan2(int* bsum, int nb) {
    if (threadIdx.x == 0 && blockIdx.x == 0) {
        int acc = 0;
        for (int i = 0; i < nb; i++) { int x = bsum[i]; bsum[i] = acc; acc += x; }
    }
}
__global__ void k_scan3(int* offs, const int* bsum, int n) {
    int i = blockIdx.x * blockDim.x + threadIdx.x;
    if (i < n) offs[i] += bsum[i >> 10];
}
// store SOURCE node ids directly (no per-edge ei gather in k_agg)
__global__ void k_scatter(const int* __restrict__ ei, const int* __restrict__ offs,
                          int* __restrict__ cursor, int* __restrict__ srcs, int E, int N) {
    int i = blockIdx.x * blockDim.x + threadIdx.x;
    if (i >= E + N) return;
    int d, s;
    if (i < E) { d = ei[E + i]; s = ei[i]; }
    else       { d = i - E;     s = i - E; }
    int pos = atomicAdd(&cursor[d], 1);
    srcs[offs[d] + pos] = s;
}

// ---------------- softmax + aggregation: one block per destination node ----------------
// 256 threads = 4 edge-slots (one wave each) x 64 channel-threads (4 ch each).
// Softmax without max subtraction (logits bounded ~|3|): mathematically identical.
__global__ __launch_bounds__(256) void k_agg(
    const int* __restrict__ offs, const int* __restrict__ srcs,
    const unsigned short* __restrict__ hb,
    const float* __restrict__ a_src, const float* __restrict__ a_dst,
    const float* __restrict__ bias_gat, const unsigned short* __restrict__ tb,
    float* __restrict__ out, int N, int E) {
    const int n = blockIdx.x;
    const int t = threadIdx.x;
    const int p = t >> 6;          // edge slot 0..3
    const int l = t & 63;          // channel group: channels 4l..4l+3
    const int head = l >> 4;
    int beg = offs[n];
    int end = (n + 1 < N) ? offs[n + 1] : (E + N);

    __shared__ int   s_src[64];
    __shared__ float s_w[64][4];
    __shared__ float s_acc[4][64][4];
    __shared__ float s_den[4][4];

    const float ad = a_dst[(long)n * 4 + p];   // note: stage threads use hh=p
    f32x4 acc = {};
    float den = 0.f;

    for (int base = beg; base < end; base += 64) {
        int len = min(64, end - base);
        // stage: thread (j = l? no: j = t&63 staged per lane) -- use j=l, hh=p
        {
            int j = l;           // edge within chunk
            int hh = p;          // head staged by this thread
            float w = 0.f;
            int src = 0;
            if (j < len) {
                src = srcs[base + j];
                float lv = a_src[(long)src * 4 + hh] + ad;
                lv = fmaxf(lv, 0.2f * lv);        // LeakyReLU(0.2)
                w = __expf(lv);
            }
            s_w[j][hh] = w;
            if (hh == 0) s_src[j] = src;
        }
        __syncthreads();
        int lenp = (len + 3) & ~3;
        for (int i = 0; i < lenp; i += 4) {
            int slot = i + p;
            float w = s_w[slot][head];
            int src = s_src[slot];
            uint2 hv = ((const uint2*)(hb + ((long)src << 8)))[l];
            den += w;
            acc[0] = fmaf(w, __uint_as_float(hv.x << 16), acc[0]);
            acc[1] = fmaf(w, __uint_as_float(hv.x & 0xFFFF0000u), acc[1]);
            acc[2] = fmaf(w, __uint_as_float(hv.y << 16), acc[2]);
            acc[3] = fmaf(w, __uint_as_float(hv.y & 0xFFFF0000u), acc[3]);
        }
        __syncthreads();
    }

    *(f32x4*)&s_acc[p][l][0] = acc;
    if ((l & 15) == 0) s_den[p][l >> 4] = den;
    __syncthreads();
    if (t < 64) {
        int lc = t;
        int hh = lc >> 4;
        f32x4 a0 = *(const f32x4*)&s_acc[0][lc][0];
        f32x4 a1 = *(const f32x4*)&s_acc[1][lc][0];
        f32x4 a2 = *(const f32x4*)&s_acc[2][lc][0];
        f32x4 a3 = *(const f32x4*)&s_acc[3][lc][0];
        f32x4 asum = a0 + a1 + a2 + a3;
        float dtot = s_den[0][hh] + s_den[1][hh] + s_den[2][hh] + s_den[3][hh];
        float inv = 1.f / (dtot + 1e-16f);
        float4 bv = ((const float4*)bias_gat)[lc];
        float4 trf;
        long rowoff = (long)n * 256 + lc * 4;
        if (tb) {
            uint2 tv = ((const uint2*)(tb + (long)n * 256))[lc];
            trf.x = __uint_as_float(tv.x << 16);
            trf.y = __uint_as_float(tv.x & 0xFFFF0000u);
            trf.z = __uint_as_float(tv.y << 16);
            trf.w = __uint_as_float(tv.y & 0xFFFF0000u);
        } else {
            trf = *(const float4*)(out + rowoff);
        }
        float4 r;
        r.x = asum[0] * inv + bv.x + trf.x;
        r.y = asum[1] * inv + bv.y + trf.y;
        r.z = asum[2] * inv + bv.z + trf.z;
        r.w = asum[3] * inv + bv.w + trf.w;
        *(float4*)(out + rowoff) = r;
    }
}

extern "C" void kernel_launch(void* const* d_in, const int* in_sizes, int n_in,
                              void* d_out, int out_size, void* d_ws, size_t ws_size,
                              hipStream_t stream) {
    const float* x        = (const float*)d_in[0];
    const int*   ei       = (const int*)d_in[1];     // harness delivers integers as int32
    const float* W_gat    = (const float*)d_in[4];
    const float* att_src  = (const float*)d_in[5];
    const float* att_dst  = (const float*)d_in[6];
    const float* bias_gat = (const float*)d_in[7];
    const float* w_ft     = (const float*)d_in[12];
    const float* b_ft     = (const float*)d_in[13];
    const float* bn_g     = (const float*)d_in[14];
    const float* bn_b     = (const float*)d_in[15];
    const float* bn_m     = (const float*)d_in[16];
    const float* bn_v     = (const float*)d_in[17];
    float* out = (float*)d_out;

    const int N = in_sizes[0] / 256;
    const int E = in_sizes[1] / 2;
    const int ETOT = E + N;

    char* p = (char*)d_ws;
    char* pend = p + ws_size;
    auto alloc = [&](size_t bytes) {
        void* r = (void*)p;
        p += (bytes + 255) & ~(size_t)255;
        return r;
    };
    unsigned short* wbt  = (unsigned short*)alloc((size_t)512 * 256 * 2);
    unsigned short* hb   = (unsigned short*)alloc((size_t)N * 256 * 2);
    float* a_src = (float*)alloc((size_t)N * 4 * 4);
    float* a_dst = (float*)alloc((size_t)N * 4 * 4);
    int* deg    = (int*)alloc((size_t)N * 4);
    int* cursor = (int*)alloc((size_t)N * 4);
    int* offs   = (int*)alloc((size_t)(N + 1) * 4);
    int* bsum   = (int*)alloc((size_t)256 * 4);
    int* srcs   = (int*)alloc((size_t)ETOT * 4);
    // optional bf16 'transformed' buffer (saves f32 round-trip through d_out)
    unsigned short* tb = (unsigned short*)alloc((size_t)N * 256 * 2);
    if (p > pend) tb = nullptr;   // ws too small -> fall back to f32 path via d_out

    k_convert_w<<<(512 * 256 + 255) / 256, 256, 0, stream>>>(W_gat, w_ft, wbt);

    dim3 gg((N + BM - 1) / BM, 4);
    k_gemm<<<gg, 256, 0, stream>>>(x, wbt, hb, tb, out, b_ft, bn_g, bn_b, bn_m, bn_v, N);

    k_attn<<<(N + 3) / 4, 256, 0, stream>>>(hb, att_src, att_dst, a_src, a_dst, N);

    k_zero2<<<(N + 255) / 256, 256, 0, stream>>>(deg, cursor, N);
    k_count<<<(ETOT + 255) / 256, 256, 0, stream>>>(ei, deg, E, N);
    int nb = (N + 1023) / 1024;
    k_scan1<<<nb, 256, 0, stream>>>(deg, offs, bsum, N);
    k_scan2<<<1, 64, 0, stream>>>(bsum, nb);
    k_scan3<<<(N + 255) / 256, 256, 0, stream>>>(offs, bsum, N);
    k_scatter<<<(ETOT + 255) / 256, 256, 0, stream>>>(ei, offs, cursor, srcs, E, N);

    k_agg<<<N, 256, 0, stream>>>(offs, srcs, hb, a_src, a_dst, bias_gat, tb, out, N, E);
}

// Round 5
// 260.561 us; speedup vs baseline: 1.1713x; 1.0546x over previous
//
#include <hip/hip_runtime.h>
#include <math.h>

typedef __attribute__((ext_vector_type(4))) float  f32x4;
typedef __attribute__((ext_vector_type(8))) short  short8;
typedef __attribute__((ext_vector_type(4))) unsigned short usx4;
typedef __attribute__((ext_vector_type(8))) unsigned short usx8;

__device__ __forceinline__ float bf2f(unsigned short u) {
    union { unsigned int i; float f; } c; c.i = ((unsigned int)u) << 16; return c.f;
}
__device__ __forceinline__ unsigned short f2bf(float f) {
    union { float f; unsigned int i; } c; c.f = f;
    unsigned int x = c.i;
    unsigned int r = (x + 0x7FFFu + ((x >> 16) & 1u)) >> 16;  // round-nearest-even
    return (unsigned short)r;
}

// ---- build WbT [512][256] bf16 (transposed, cols 0-255 = W_gat, 256-511 = w_ft) ----
__global__ __launch_bounds__(256) void k_convert_w(const float* __restrict__ Wg,
                                                   const float* __restrict__ Wf,
                                                   unsigned short* __restrict__ wbt) {
    int idx = blockIdx.x * blockDim.x + threadIdx.x;
    if (idx >= 512 * 256) return;
    int c = idx >> 8;
    int k = idx & 255;
    float v = (c < 256) ? Wg[k * 256 + c] : Wf[k * 256 + (c - 256)];
    wbt[idx] = f2bf(v);
}

// ---------------- fused GEMM: [h | transformed] = x @ [W_gat | w_ft] ----------------
#define BM 128
#define BN 128
#define BK 32
__global__ __launch_bounds__(256) void k_gemm(
    const float* __restrict__ x,              // [M][256] f32
    const unsigned short* __restrict__ wbt,   // [512][256] bf16
    unsigned short* __restrict__ hb,          // [M][256] bf16 (GAT h)
    unsigned short* __restrict__ tb,          // [M][256] bf16 transformed (or null)
    float* __restrict__ out,                  // fallback f32 transformed target
    const float* __restrict__ b_ft, const float* __restrict__ bn_g,
    const float* __restrict__ bn_b, const float* __restrict__ bn_m,
    const float* __restrict__ bn_v, int M) {
    __shared__ unsigned short As[BM][BK + 8];
    __shared__ unsigned short Bs[BN][BK + 8];
    const int t = threadIdx.x;
    const int w = t >> 6, lane = t & 63;
    const int wr = w >> 1, wc = w & 1;
    const int bm0 = blockIdx.x * BM;
    const int bn0 = blockIdx.y * BN;
    const int kg = lane >> 4;
    const int lm = lane & 15;

    f32x4 acc[4][4] = {};

    for (int k0 = 0; k0 < 256; k0 += BK) {
        f32x4 a0[2], a1[2];
        usx8 bv[2];
#pragma unroll
        for (int s = 0; s < 2; s++) {
            int seg = t + s * 256;
            int row = seg >> 2;
            int off = (seg & 3) * 8;
            int grow = bm0 + row; if (grow >= M) grow = M - 1;
            const float* ap = x + (long)grow * 256 + k0 + off;
            a0[s] = *(const f32x4*)ap;
            a1[s] = *(const f32x4*)(ap + 4);
            bv[s] = *(const usx8*)(wbt + (long)(bn0 + row) * 256 + k0 + off);
        }
        __syncthreads();
#pragma unroll
        for (int s = 0; s < 2; s++) {
            int seg = t + s * 256;
            int row = seg >> 2;
            int off = (seg & 3) * 8;
            usx8 av;
            av[0] = f2bf(a0[s][0]); av[1] = f2bf(a0[s][1]);
            av[2] = f2bf(a0[s][2]); av[3] = f2bf(a0[s][3]);
            av[4] = f2bf(a1[s][0]); av[5] = f2bf(a1[s][1]);
            av[6] = f2bf(a1[s][2]); av[7] = f2bf(a1[s][3]);
            *(usx8*)&As[row][off] = av;
            *(usx8*)&Bs[row][off] = bv[s];
        }
        __syncthreads();
        short8 afr[4], bfr[4];
#pragma unroll
        for (int mi = 0; mi < 4; mi++)
            afr[mi] = *(const short8*)&As[wr * 64 + mi * 16 + lm][kg * 8];
#pragma unroll
        for (int nj = 0; nj < 4; nj++)
            bfr[nj] = *(const short8*)&Bs[wc * 64 + nj * 16 + lm][kg * 8];
#pragma unroll
        for (int mi = 0; mi < 4; mi++)
#pragma unroll
            for (int nj = 0; nj < 4; nj++)
                acc[mi][nj] = __builtin_amdgcn_mfma_f32_16x16x32_bf16(
                    afr[mi], bfr[nj], acc[mi][nj], 0, 0, 0);
        __syncthreads();
    }

    const bool isH = (bn0 < 256);
#pragma unroll
    for (int mi = 0; mi < 4; mi++) {
#pragma unroll
        for (int nj = 0; nj < 4; nj++) {
            int col = bn0 + wc * 64 + nj * 16 + lm;
            f32x4 a = acc[mi][nj];
            int rowbase = bm0 + wr * 64 + mi * 16 + kg * 4;
            if (isH) {
#pragma unroll
                for (int r = 0; r < 4; r++) {
                    int row = rowbase + r;
                    if (row < M) hb[(long)row * 256 + col] = f2bf(a[r]);
                }
            } else {
                int c2 = col - 256;
                float bft = b_ft[c2], mu = bn_m[c2];
                float iv = rsqrtf(bn_v[c2] + 1e-5f);
                float g = bn_g[c2], bt = bn_b[c2];
#pragma unroll
                for (int r = 0; r < 4; r++) {
                    int row = rowbase + r;
                    if (row < M) {
                        float v = (a[r] + bft - mu) * iv * g + bt;
                        v = v > 0.f ? v : 0.f;
                        if (tb) tb[(long)row * 256 + c2] = f2bf(v);
                        else    out[(long)row * 256 + c2] = v;
                    }
                }
            }
        }
    }
}

// ---------------- per-node attention coefficients: a_src/a_dst [N][4] ----------------
__global__ __launch_bounds__(256) void k_attn(const unsigned short* __restrict__ hb,
                                              const float* __restrict__ att_s,
                                              const float* __restrict__ att_d,
                                              float* __restrict__ a_src,
                                              float* __restrict__ a_dst, int N) {
    int gid = blockIdx.x * 256 + threadIdx.x;
    int node = gid >> 6;
    int lane = threadIdx.x & 63;
    if (node >= N) return;
    usx4 hv = ((const usx4*)(hb + (long)node * 256))[lane];
    int head = lane >> 4;
    int cb = (lane & 15) * 4;
    float s1 = 0.f, s2 = 0.f;
#pragma unroll
    for (int j = 0; j < 4; j++) {
        float h = bf2f(hv[j]);
        s1 += h * att_s[head * 64 + cb + j];
        s2 += h * att_d[head * 64 + cb + j];
    }
#pragma unroll
    for (int o = 1; o < 16; o <<= 1) {
        s1 += __shfl_xor(s1, o);
        s2 += __shfl_xor(s2, o);
    }
    if ((lane & 15) == 0) {
        a_src[node * 4 + head] = s1;
        a_dst[node * 4 + head] = s2;
    }
}

// ---------------- CSR build (edge_index is int32) ----------------
__global__ void k_count(const int* __restrict__ ei, int* __restrict__ deg,
                        int E, int N) {
    int i = blockIdx.x * blockDim.x + threadIdx.x;
    if (i >= E + N) return;
    int d = (i < E) ? ei[E + i] : (i - E);
    atomicAdd(&deg[d], 1);
}
__global__ __launch_bounds__(256) void k_scan1(const int* __restrict__ deg,
                                               int* __restrict__ offs,
                                               int* __restrict__ bsum, int n) {
    __shared__ int tmp[256];
    int b = blockIdx.x, t = threadIdx.x;
    int base = b * 1024;
    int v[4];
#pragma unroll
    for (int j = 0; j < 4; j++) {
        int i = base + t * 4 + j;
        v[j] = (i < n) ? deg[i] : 0;
    }
    int local = v[0] + v[1] + v[2] + v[3];
    tmp[t] = local;
    __syncthreads();
    for (int off = 1; off < 256; off <<= 1) {
        int xv = (t >= off) ? tmp[t - off] : 0;
        __syncthreads();
        tmp[t] += xv;
        __syncthreads();
    }
    int run = tmp[t] - local;
    if (t == 255) bsum[b] = tmp[255];
#pragma unroll
    for (int j = 0; j < 4; j++) {
        int i = base + t * 4 + j;
        if (i < n) offs[i] = run;
        run += v[j];
    }
}
__global__ void k_scan2(int* bsum, int nb) {
    if (threadIdx.x == 0 && blockIdx.x == 0) {
        int acc = 0;
        for (int i = 0; i < nb; i++) { int x = bsum[i]; bsum[i] = acc; acc += x; }
    }
}
__global__ void k_scan3(int* offs, const int* bsum, int n) {
    int i = blockIdx.x * blockDim.x + threadIdx.x;
    if (i < n) offs[i] += bsum[i >> 10];
}
// store SOURCE node ids directly (no per-edge ei gather in k_agg)
__global__ void k_scatter(const int* __restrict__ ei, const int* __restrict__ offs,
                          int* __restrict__ cursor, int* __restrict__ srcs, int E, int N) {
    int i = blockIdx.x * blockDim.x + threadIdx.x;
    if (i >= E + N) return;
    int d, s;
    if (i < E) { d = ei[E + i]; s = ei[i]; }
    else       { d = i - E;     s = i - E; }
    int pos = atomicAdd(&cursor[d], 1);
    srcs[offs[d] + pos] = s;
}

// ---------------- softmax + aggregation: ONE WAVE per destination node ----------------
// No LDS, no barriers. Lane l owns channels 4l..4l+3 (head = l>>4).
// Softmax without max subtraction (logits bounded ~|4|): mathematically identical.
__global__ __launch_bounds__(256) void k_agg(
    const int* __restrict__ offs, const int* __restrict__ srcs,
    const unsigned short* __restrict__ hb,
    const float* __restrict__ a_src, const float* __restrict__ a_dst,
    const float* __restrict__ bias_gat, const unsigned short* __restrict__ tb,
    float* __restrict__ out, int N, int E) {
    const int n = (blockIdx.x * 256 + threadIdx.x) >> 6;   // node = global wave id
    const int l = threadIdx.x & 63;
    if (n >= N) return;
    const int head = l >> 4;
    const int beg = offs[n];
    const int end = (n + 1 < N) ? offs[n + 1] : (E + N);

    const float ad = a_dst[(long)n * 4 + head];
    f32x4 acc = {};
    float den = 0.f;

    for (int base = beg; base < end; base += 64) {
        const int len = min(64, end - base);
        int sv = (base + l < end) ? srcs[base + l] : 0;
        for (int i = 0; i < len; ++i) {
            int src = __shfl(sv, i);
            float as = a_src[(long)src * 4 + head];
            float lv = as + ad;
            lv = fmaxf(lv, 0.2f * lv);            // LeakyReLU(0.2)
            float wgt = __expf(lv);
            uint2 hv = ((const uint2*)(hb + ((long)src << 8)))[l];
            den += wgt;
            acc[0] = fmaf(wgt, __uint_as_float(hv.x << 16), acc[0]);
            acc[1] = fmaf(wgt, __uint_as_float(hv.x & 0xFFFF0000u), acc[1]);
            acc[2] = fmaf(wgt, __uint_as_float(hv.y << 16), acc[2]);
            acc[3] = fmaf(wgt, __uint_as_float(hv.y & 0xFFFF0000u), acc[3]);
        }
    }

    const float inv = 1.f / (den + 1e-16f);
    const float4 bv = ((const float4*)bias_gat)[l];
    float4 trf;
    const long rowoff = ((long)n << 8) + l * 4;
    if (tb) {
        uint2 tv = ((const uint2*)(tb + ((long)n << 8)))[l];
        trf.x = __uint_as_float(tv.x << 16);
        trf.y = __uint_as_float(tv.x & 0xFFFF0000u);
        trf.z = __uint_as_float(tv.y << 16);
        trf.w = __uint_as_float(tv.y & 0xFFFF0000u);
    } else {
        trf = *(const float4*)(out + rowoff);
    }
    float4 r;
    r.x = acc[0] * inv + bv.x + trf.x;
    r.y = acc[1] * inv + bv.y + trf.y;
    r.z = acc[2] * inv + bv.z + trf.z;
    r.w = acc[3] * inv + bv.w + trf.w;
    *(float4*)(out + rowoff) = r;
}

extern "C" void kernel_launch(void* const* d_in, const int* in_sizes, int n_in,
                              void* d_out, int out_size, void* d_ws, size_t ws_size,
                              hipStream_t stream) {
    const float* x        = (const float*)d_in[0];
    const int*   ei       = (const int*)d_in[1];     // harness delivers integers as int32
    const float* W_gat    = (const float*)d_in[4];
    const float* att_src  = (const float*)d_in[5];
    const float* att_dst  = (const float*)d_in[6];
    const float* bias_gat = (const float*)d_in[7];
    const float* w_ft     = (const float*)d_in[12];
    const float* b_ft     = (const float*)d_in[13];
    const float* bn_g     = (const float*)d_in[14];
    const float* bn_b     = (const float*)d_in[15];
    const float* bn_m     = (const float*)d_in[16];
    const float* bn_v     = (const float*)d_in[17];
    float* out = (float*)d_out;

    const int N = in_sizes[0] / 256;
    const int E = in_sizes[1] / 2;
    const int ETOT = E + N;

    char* p = (char*)d_ws;
    char* pend = p + ws_size;
    auto alloc = [&](size_t bytes) {
        void* r = (void*)p;
        p += (bytes + 255) & ~(size_t)255;
        return r;
    };
    unsigned short* wbt  = (unsigned short*)alloc((size_t)512 * 256 * 2);
    unsigned short* hb   = (unsigned short*)alloc((size_t)N * 256 * 2);
    float* a_src = (float*)alloc((size_t)N * 4 * 4);
    float* a_dst = (float*)alloc((size_t)N * 4 * 4);
    int* deg    = (int*)alloc((size_t)N * 4);        // deg+cursor adjacent: one memset
    int* cursor = (int*)alloc((size_t)N * 4);
    int* offs   = (int*)alloc((size_t)(N + 1) * 4);
    int* bsum   = (int*)alloc((size_t)256 * 4);
    int* srcs   = (int*)alloc((size_t)ETOT * 4);
    unsigned short* tb = (unsigned short*)alloc((size_t)N * 256 * 2);
    if (p > pend) tb = nullptr;   // ws too small -> fall back to f32 path via d_out

    k_convert_w<<<(512 * 256 + 255) / 256, 256, 0, stream>>>(W_gat, w_ft, wbt);

    dim3 gg((N + BM - 1) / BM, 4);
    k_gemm<<<gg, 256, 0, stream>>>(x, wbt, hb, tb, out, b_ft, bn_g, bn_b, bn_m, bn_v, N);

    k_attn<<<(N + 3) / 4, 256, 0, stream>>>(hb, att_src, att_dst, a_src, a_dst, N);

    // deg and cursor are adjacent 256B-aligned carves; zero both in one memset
    hipMemsetAsync(deg, 0, ((size_t)N * 4 + 255 & ~(size_t)255) + (size_t)N * 4, stream);
    k_count<<<(ETOT + 255) / 256, 256, 0, stream>>>(ei, deg, E, N);
    int nb = (N + 1023) / 1024;
    k_scan1<<<nb, 256, 0, stream>>>(deg, offs, bsum, N);
    k_scan2<<<1, 64, 0, stream>>>(bsum, nb);
    k_scan3<<<(N + 255) / 256, 256, 0, stream>>>(offs, bsum, N);
    k_scatter<<<(ETOT + 255) / 256, 256, 0, stream>>>(ei, offs, cursor, srcs, E, N);

    k_agg<<<(N * 64 + 255) / 256, 256, 0, stream>>>(offs, srcs, hb, a_src, a_dst,
                                                    bias_gat, tb, out, N, E);
}

// Round 6
// 251.606 us; speedup vs baseline: 1.2130x; 1.0356x over previous
//
#include <hip/hip_runtime.h>
#include <math.h>

typedef __attribute__((ext_vector_type(4))) float  f32x4;
typedef __attribute__((ext_vector_type(8))) short  short8;
typedef __attribute__((ext_vector_type(4))) unsigned short usx4;
typedef __attribute__((ext_vector_type(8))) unsigned short usx8;

__device__ __forceinline__ float bf2f(unsigned short u) {
    union { unsigned int i; float f; } c; c.i = ((unsigned int)u) << 16; return c.f;
}
__device__ __forceinline__ unsigned short f2bf(float f) {
    union { float f; unsigned int i; } c; c.f = f;
    unsigned int x = c.i;
    unsigned int r = (x + 0x7FFFu + ((x >> 16) & 1u)) >> 16;  // round-nearest-even
    return (unsigned short)r;
}

// ---------------- convert x (f32 -> bf16), 8 elems/thread ----------------
__global__ __launch_bounds__(256) void k_convert_x(const float* __restrict__ x,
                                                   unsigned short* __restrict__ xb,
                                                   long total8) {
    long i = (long)blockIdx.x * blockDim.x + threadIdx.x;
    if (i >= total8) return;
    const f32x4* p = (const f32x4*)x;
    f32x4 v0 = p[2 * i], v1 = p[2 * i + 1];
    usx8 o;
    o[0] = f2bf(v0[0]); o[1] = f2bf(v0[1]); o[2] = f2bf(v0[2]); o[3] = f2bf(v0[3]);
    o[4] = f2bf(v1[0]); o[5] = f2bf(v1[1]); o[6] = f2bf(v1[2]); o[7] = f2bf(v1[3]);
    ((usx8*)xb)[i] = o;
}

// ---- build WbT [512][256] bf16 (transposed, cols 0-255 = W_gat, 256-511 = w_ft) ----
__global__ __launch_bounds__(256) void k_convert_w(const float* __restrict__ Wg,
                                                   const float* __restrict__ Wf,
                                                   unsigned short* __restrict__ wbt) {
    int idx = blockIdx.x * blockDim.x + threadIdx.x;
    if (idx >= 512 * 256) return;
    int c = idx >> 8;
    int k = idx & 255;
    float v = (c < 256) ? Wg[k * 256 + c] : Wf[k * 256 + (c - 256)];
    wbt[idx] = f2bf(v);
}

// ---------------- fused GEMM: [h | transformed] = x @ [W_gat | w_ft] ----------------
#define BM 128
#define BN 128
#define BK 32
__global__ __launch_bounds__(256) void k_gemm(
    const float* __restrict__ x,              // [M][256] f32 (fallback)
    const unsigned short* __restrict__ xb,    // [M][256] bf16 (preferred, may be null)
    const unsigned short* __restrict__ wbt,   // [512][256] bf16
    unsigned short* __restrict__ hb,          // [M][256] bf16 (GAT h)
    unsigned short* __restrict__ tb,          // [M][256] bf16 transformed (or null)
    float* __restrict__ out,                  // fallback f32 transformed target
    const float* __restrict__ b_ft, const float* __restrict__ bn_g,
    const float* __restrict__ bn_b, const float* __restrict__ bn_m,
    const float* __restrict__ bn_v, int M) {
    __shared__ unsigned short As[BM][BK + 8];
    __shared__ unsigned short Bs[BN][BK + 8];
    const int t = threadIdx.x;
    const int w = t >> 6, lane = t & 63;
    const int wr = w >> 1, wc = w & 1;
    const int bm0 = blockIdx.x * BM;
    const int bn0 = blockIdx.y * BN;
    const int kg = lane >> 4;
    const int lm = lane & 15;

    f32x4 acc[4][4] = {};

    for (int k0 = 0; k0 < 256; k0 += BK) {
        if (xb) {
            usx8 avv[2], bvv[2];
#pragma unroll
            for (int s = 0; s < 2; s++) {
                int seg = t + s * 256;          // 0..511
                int row = seg >> 2;             // 0..127
                int off = (seg & 3) * 8;
                int grow = bm0 + row; if (grow >= M) grow = M - 1;
                avv[s] = *(const usx8*)(xb + (long)grow * 256 + k0 + off);
                bvv[s] = *(const usx8*)(wbt + (long)(bn0 + row) * 256 + k0 + off);
            }
            __syncthreads();
#pragma unroll
            for (int s = 0; s < 2; s++) {
                int seg = t + s * 256;
                int row = seg >> 2;
                int off = (seg & 3) * 8;
                *(usx8*)&As[row][off] = avv[s];
                *(usx8*)&Bs[row][off] = bvv[s];
            }
        } else {
            f32x4 a0[2], a1[2];
            usx8 bv[2];
#pragma unroll
            for (int s = 0; s < 2; s++) {
                int seg = t + s * 256;
                int row = seg >> 2;
                int off = (seg & 3) * 8;
                int grow = bm0 + row; if (grow >= M) grow = M - 1;
                const float* ap = x + (long)grow * 256 + k0 + off;
                a0[s] = *(const f32x4*)ap;
                a1[s] = *(const f32x4*)(ap + 4);
                bv[s] = *(const usx8*)(wbt + (long)(bn0 + row) * 256 + k0 + off);
            }
            __syncthreads();
#pragma unroll
            for (int s = 0; s < 2; s++) {
                int seg = t + s * 256;
                int row = seg >> 2;
                int off = (seg & 3) * 8;
                usx8 av;
                av[0] = f2bf(a0[s][0]); av[1] = f2bf(a0[s][1]);
                av[2] = f2bf(a0[s][2]); av[3] = f2bf(a0[s][3]);
                av[4] = f2bf(a1[s][0]); av[5] = f2bf(a1[s][1]);
                av[6] = f2bf(a1[s][2]); av[7] = f2bf(a1[s][3]);
                *(usx8*)&As[row][off] = av;
                *(usx8*)&Bs[row][off] = bv[s];
            }
        }
        __syncthreads();
        short8 afr[4], bfr[4];
#pragma unroll
        for (int mi = 0; mi < 4; mi++)
            afr[mi] = *(const short8*)&As[wr * 64 + mi * 16 + lm][kg * 8];
#pragma unroll
        for (int nj = 0; nj < 4; nj++)
            bfr[nj] = *(const short8*)&Bs[wc * 64 + nj * 16 + lm][kg * 8];
#pragma unroll
        for (int mi = 0; mi < 4; mi++)
#pragma unroll
            for (int nj = 0; nj < 4; nj++)
                acc[mi][nj] = __builtin_amdgcn_mfma_f32_16x16x32_bf16(
                    afr[mi], bfr[nj], acc[mi][nj], 0, 0, 0);
        __syncthreads();
    }

    const bool isH = (bn0 < 256);
#pragma unroll
    for (int mi = 0; mi < 4; mi++) {
#pragma unroll
        for (int nj = 0; nj < 4; nj++) {
            int col = bn0 + wc * 64 + nj * 16 + lm;
            f32x4 a = acc[mi][nj];
            int rowbase = bm0 + wr * 64 + mi * 16 + kg * 4;
            if (isH) {
#pragma unroll
                for (int r = 0; r < 4; r++) {
                    int row = rowbase + r;
                    if (row < M) hb[(long)row * 256 + col] = f2bf(a[r]);
                }
            } else {
                int c2 = col - 256;
                float bft = b_ft[c2], mu = bn_m[c2];
                float iv = rsqrtf(bn_v[c2] + 1e-5f);
                float g = bn_g[c2], bt = bn_b[c2];
#pragma unroll
                for (int r = 0; r < 4; r++) {
                    int row = rowbase + r;
                    if (row < M) {
                        float v = (a[r] + bft - mu) * iv * g + bt;
                        v = v > 0.f ? v : 0.f;
                        if (tb) tb[(long)row * 256 + c2] = f2bf(v);
                        else    out[(long)row * 256 + c2] = v;
                    }
                }
            }
        }
    }
}

// ---------------- per-node attention coefficients: a_src/a_dst [N][4] ----------------
__global__ __launch_bounds__(256) void k_attn(const unsigned short* __restrict__ hb,
                                              const float* __restrict__ att_s,
                                              const float* __restrict__ att_d,
                                              float* __restrict__ a_src,
                                              float* __restrict__ a_dst, int N) {
    int gid = blockIdx.x * 256 + threadIdx.x;
    int node = gid >> 6;
    int lane = threadIdx.x & 63;
    if (node >= N) return;
    usx4 hv = ((const usx4*)(hb + (long)node * 256))[lane];
    int head = lane >> 4;
    int cb = (lane & 15) * 4;
    float s1 = 0.f, s2 = 0.f;
#pragma unroll
    for (int j = 0; j < 4; j++) {
        float h = bf2f(hv[j]);
        s1 += h * att_s[head * 64 + cb + j];
        s2 += h * att_d[head * 64 + cb + j];
    }
#pragma unroll
    for (int o = 1; o < 16; o <<= 1) {
        s1 += __shfl_xor(s1, o);
        s2 += __shfl_xor(s2, o);
    }
    if ((lane & 15) == 0) {
        a_src[node * 4 + head] = s1;
        a_dst[node * 4 + head] = s2;
    }
}

// ---------------- CSR build (edge_index is int32) ----------------
__global__ void k_count(const int* __restrict__ ei, int* __restrict__ deg,
                        int E, int N) {
    int i = blockIdx.x * blockDim.x + threadIdx.x;
    if (i >= E + N) return;
    int d = (i < E) ? ei[E + i] : (i - E);
    atomicAdd(&deg[d], 1);
}
__global__ __launch_bounds__(256) void k_scan1(const int* __restrict__ deg,
                                               int* __restrict__ offs,
                                               int* __restrict__ bsum, int n) {
    __shared__ int tmp[256];
    int b = blockIdx.x, t = threadIdx.x;
    int base = b * 1024;
    int v[4];
#pragma unroll
    for (int j = 0; j < 4; j++) {
        int i = base + t * 4 + j;
        v[j] = (i < n) ? deg[i] : 0;
    }
    int local = v[0] + v[1] + v[2] + v[3];
    tmp[t] = local;
    __syncthreads();
    for (int off = 1; off < 256; off <<= 1) {
        int xv = (t >= off) ? tmp[t - off] : 0;
        __syncthreads();
        tmp[t] += xv;
        __syncthreads();
    }
    int run = tmp[t] - local;
    if (t == 255) bsum[b] = tmp[255];
#pragma unroll
    for (int j = 0; j < 4; j++) {
        int i = base + t * 4 + j;
        if (i < n) offs[i] = run;
        run += v[j];
    }
}
__global__ void k_scan2(int* bsum, int nb) {
    if (threadIdx.x == 0 && blockIdx.x == 0) {
        int acc = 0;
        for (int i = 0; i < nb; i++) { int x = bsum[i]; bsum[i] = acc; acc += x; }
    }
}
__global__ void k_scan3(int* offs, const int* bsum, int n) {
    int i = blockIdx.x * blockDim.x + threadIdx.x;
    if (i < n) offs[i] += bsum[i >> 10];
}
// store SOURCE node ids directly (no per-edge ei gather in k_agg)
__global__ void k_scatter(const int* __restrict__ ei, const int* __restrict__ offs,
                          int* __restrict__ cursor, int* __restrict__ srcs, int E, int N) {
    int i = blockIdx.x * blockDim.x + threadIdx.x;
    if (i >= E + N) return;
    int d, s;
    if (i < E) { d = ei[E + i]; s = ei[i]; }
    else       { d = i - E;     s = i - E; }
    int pos = atomicAdd(&cursor[d], 1);
    srcs[offs[d] + pos] = s;
}

// ---------------- softmax + aggregation: ONE WAVE per destination node ----------------
// 16-edge chunks. Stage: lane l computes exp-weight of edge (base + (l&15)) for
// head (l>>4). Inner loop (unrolled when len==16): constant-lane shuffles become
// readlane -> SGPR base for the hb row gather; 16 loads in flight per wave.
__global__ __launch_bounds__(256) void k_agg(
    const int* __restrict__ offs, const int* __restrict__ srcs,
    const unsigned short* __restrict__ hb,
    const float* __restrict__ a_src, const float* __restrict__ a_dst,
    const float* __restrict__ bias_gat, const unsigned short* __restrict__ tb,
    float* __restrict__ out, int N, int E) {
    const int n = (blockIdx.x * 256 + threadIdx.x) >> 6;   // node = global wave id
    const int l = threadIdx.x & 63;
    if (n >= N) return;
    const int head = l >> 4;
    const int sub = l & 15;
    const int beg = offs[n];
    const int end = (n + 1 < N) ? offs[n + 1] : (E + N);

    const float ad = a_dst[(long)n * 4 + head];
    f32x4 acc = {};
    float den = 0.f;

    for (int base = beg; base < end; base += 16) {
        const int len = min(16, end - base);
        // stage weights for this chunk
        int sv = 0;
        float wsel = 0.f;
        if (base + sub < end) {
            sv = srcs[base + sub];
            float lv = a_src[(long)sv * 4 + head] + ad;
            lv = fmaxf(lv, 0.2f * lv);            // LeakyReLU(0.2)
            wsel = __expf(lv);
        }

#define AGG_EDGE(i)                                                        \
        {                                                                  \
            int src = __shfl(sv, (i));                                     \
            float wgt = __shfl(wsel, (l & 48) + (i));                      \
            uint2 hv = ((const uint2*)(hb + ((long)src << 8)))[l];         \
            den += wgt;                                                    \
            acc[0] = fmaf(wgt, __uint_as_float(hv.x << 16), acc[0]);       \
            acc[1] = fmaf(wgt, __uint_as_float(hv.x & 0xFFFF0000u), acc[1]);\
            acc[2] = fmaf(wgt, __uint_as_float(hv.y << 16), acc[2]);       \
            acc[3] = fmaf(wgt, __uint_as_float(hv.y & 0xFFFF0000u), acc[3]);\
        }

        if (len == 16) {
#pragma unroll
            for (int i = 0; i < 16; ++i) AGG_EDGE(i)
        } else {
            for (int i = 0; i < len; ++i) AGG_EDGE(i)
        }
#undef AGG_EDGE
    }

    const float inv = 1.f / (den + 1e-16f);
    const float4 bv = ((const float4*)bias_gat)[l];
    float4 trf;
    const long rowoff = ((long)n << 8) + l * 4;
    if (tb) {
        uint2 tv = ((const uint2*)(tb + ((long)n << 8)))[l];
        trf.x = __uint_as_float(tv.x << 16);
        trf.y = __uint_as_float(tv.x & 0xFFFF0000u);
        trf.z = __uint_as_float(tv.y << 16);
        trf.w = __uint_as_float(tv.y & 0xFFFF0000u);
    } else {
        trf = *(const float4*)(out + rowoff);
    }
    float4 r;
    r.x = acc[0] * inv + bv.x + trf.x;
    r.y = acc[1] * inv + bv.y + trf.y;
    r.z = acc[2] * inv + bv.z + trf.z;
    r.w = acc[3] * inv + bv.w + trf.w;
    *(float4*)(out + rowoff) = r;
}

extern "C" void kernel_launch(void* const* d_in, const int* in_sizes, int n_in,
                              void* d_out, int out_size, void* d_ws, size_t ws_size,
                              hipStream_t stream) {
    const float* x        = (const float*)d_in[0];
    const int*   ei       = (const int*)d_in[1];     // harness delivers integers as int32
    const float* W_gat    = (const float*)d_in[4];
    const float* att_src  = (const float*)d_in[5];
    const float* att_dst  = (const float*)d_in[6];
    const float* bias_gat = (const float*)d_in[7];
    const float* w_ft     = (const float*)d_in[12];
    const float* b_ft     = (const float*)d_in[13];
    const float* bn_g     = (const float*)d_in[14];
    const float* bn_b     = (const float*)d_in[15];
    const float* bn_m     = (const float*)d_in[16];
    const float* bn_v     = (const float*)d_in[17];
    float* out = (float*)d_out;

    const int N = in_sizes[0] / 256;
    const int E = in_sizes[1] / 2;
    const int ETOT = E + N;

    char* p = (char*)d_ws;
    char* pend = p + ws_size;
    auto alloc = [&](size_t bytes) {
        void* r = (void*)p;
        p += (bytes + 255) & ~(size_t)255;
        return r;
    };
    unsigned short* wbt  = (unsigned short*)alloc((size_t)512 * 256 * 2);
    unsigned short* hb   = (unsigned short*)alloc((size_t)N * 256 * 2);
    float* a_src = (float*)alloc((size_t)N * 4 * 4);
    float* a_dst = (float*)alloc((size_t)N * 4 * 4);
    int* deg    = (int*)alloc((size_t)N * 4);        // deg+cursor adjacent: one memset
    int* cursor = (int*)alloc((size_t)N * 4);
    int* offs   = (int*)alloc((size_t)(N + 1) * 4);
    int* bsum   = (int*)alloc((size_t)256 * 4);
    int* srcs   = (int*)alloc((size_t)ETOT * 4);
    unsigned short* xb = (unsigned short*)alloc((size_t)N * 256 * 2);
    if (p > pend) xb = nullptr;
    unsigned short* tb = (unsigned short*)alloc((size_t)N * 256 * 2);
    if (p > pend) tb = nullptr;

    k_convert_w<<<(512 * 256 + 255) / 256, 256, 0, stream>>>(W_gat, w_ft, wbt);
    if (xb) {
        long total8 = (long)N * 256 / 8;
        k_convert_x<<<(int)((total8 + 255) / 256), 256, 0, stream>>>(x, xb, total8);
    }

    dim3 gg((N + BM - 1) / BM, 4);
    k_gemm<<<gg, 256, 0, stream>>>(x, xb, wbt, hb, tb, out, b_ft, bn_g, bn_b, bn_m, bn_v, N);

    k_attn<<<(N + 3) / 4, 256, 0, stream>>>(hb, att_src, att_dst, a_src, a_dst, N);

    // deg and cursor are adjacent 256B-aligned carves; zero both in one memset
    hipMemsetAsync(deg, 0, (((size_t)N * 4 + 255) & ~(size_t)255) + (size_t)N * 4, stream);
    k_count<<<(ETOT + 255) / 256, 256, 0, stream>>>(ei, deg, E, N);
    int nb = (N + 1023) / 1024;
    k_scan1<<<nb, 256, 0, stream>>>(deg, offs, bsum, N);
    k_scan2<<<1, 64, 0, stream>>>(bsum, nb);
    k_scan3<<<(N + 255) / 256, 256, 0, stream>>>(offs, bsum, N);
    k_scatter<<<(ETOT + 255) / 256, 256, 0, stream>>>(ei, offs, cursor, srcs, E, N);

    k_agg<<<(N * 64 + 255) / 256, 256, 0, stream>>>(offs, srcs, hb, a_src, a_dst,
                                                    bias_gat, tb, out, N, E);
}